// Round 4
// baseline (116.561 us; speedup 1.0000x reference)
//
#include <hip/hip_runtime.h>
#include <cmath>

#define Bn 4
#define Hn 12
#define BH 48
#define Nn 8192
#define Dn 64

typedef float f32x4 __attribute__((ext_vector_type(4)));
typedef short bf16x8 __attribute__((ext_vector_type(8)));

__device__ __forceinline__ unsigned cvt_pk_bf16(float lo, float hi) {
    unsigned r;
    asm("v_cvt_pk_bf16_f32 %0, %1, %2" : "=v"(r) : "v"(lo), "v"(hi));
    return r;
}

union F16 { float4 v[4]; float f[16]; };

// ---------------- Phase 1: partial KtV^T[e][d] = sum_n (rf*k)[n,d]*v[n,e] ---
// Wave-private: each wave processes its own 32-row chunks in private LDS,
// no __syncthreads in the main loop. rf = scale*m^2/max(||k||,eps).
__global__ __launch_bounds__(256, 3) void ktv_kernel(
    const float* __restrict__ K, const float* __restrict__ V,
    const float* __restrict__ mask, float* __restrict__ partial,
    float scale, int ch)
{
    const int chunk = blockIdx.x, head = blockIdx.y;
    const int bb = head / Hn;
    const int rowsPer = Nn / ch;          // divisible by 128
    const int waveRows = rowsPer >> 2;

    const int t = threadIdx.x;
    const int w = t >> 6, l = t & 63;
    const int p = l & 15, q = l >> 4;
    const int gq = q << 3;                // swizzle for this lane's d-columns

    const size_t base = ((size_t)head * Nn + (size_t)chunk * rowsPer + (size_t)w * waveRows) * Dn;
    const float* Kp = K + base;
    const float* Vp = V + base;
    const float* mp = mask + (size_t)bb * Nn + (size_t)chunk * rowsPer + (size_t)w * waveRows;

    __shared__ __align__(16) ushort S[16384];   // 32 KB: 8 KB per wave
    ushort* sKT = S + w * 4096;                 // [d][n^g(d)] 64x32 bf16
    ushort* sVT = sKT + 2048;                   // [e][n^g(e)] 64x32 bf16

    f32x4 acc[4][4];
    #pragma unroll
    for (int a = 0; a < 4; ++a)
        #pragma unroll
        for (int b2 = 0; b2 < 4; ++b2) acc[a][b2] = (f32x4){0.f, 0.f, 0.f, 0.f};

    const int r0 = 2 * p, r1 = r0 + 1;   // this lane's two n-rows per chunk
    const int cb = 16 * q;               // this lane's 16 feature columns

    F16 ka, kb, va, vb;
    float m0, m1;
    #pragma unroll
    for (int i = 0; i < 4; ++i) {
        ka.v[i] = *(const float4*)(Kp + (size_t)r0 * Dn + cb + 4 * i);
        kb.v[i] = *(const float4*)(Kp + (size_t)r1 * Dn + cb + 4 * i);
        va.v[i] = *(const float4*)(Vp + (size_t)r0 * Dn + cb + 4 * i);
        vb.v[i] = *(const float4*)(Vp + (size_t)r1 * Dn + cb + 4 * i);
    }
    m0 = mp[r0]; m1 = mp[r1];

    const int nt = waveRows >> 5;
    for (int c = 0; c < nt; ++c) {
        // row norms: lane-local partial + 2-step reduce over q-lanes
        float ss0 = 0.f, ss1 = 0.f;
        #pragma unroll
        for (int i = 0; i < 16; ++i) { ss0 += ka.f[i] * ka.f[i]; ss1 += kb.f[i] * kb.f[i]; }
        ss0 += __shfl_xor(ss0, 16, 64); ss0 += __shfl_xor(ss0, 32, 64);
        ss1 += __shfl_xor(ss1, 16, 64); ss1 += __shfl_xor(ss1, 32, 64);
        const float rf0 = scale * m0 * m0 / fmaxf(sqrtf(ss0), 1e-12f);
        const float rf1 = scale * m1 * m1 / fmaxf(sqrtf(ss1), 1e-12f);

        // stage (wave-private, packed n-pairs, swizzled)
        const int np = r0 ^ gq;
        #pragma unroll
        for (int j = 0; j < 16; ++j)
            *(unsigned*)&sVT[(cb + j) * 32 + np] = cvt_pk_bf16(va.f[j], vb.f[j]);
        #pragma unroll
        for (int j = 0; j < 16; ++j)
            *(unsigned*)&sKT[(cb + j) * 32 + np] = cvt_pk_bf16(ka.f[j] * rf0, kb.f[j] * rf1);

        // prefetch next chunk's K + mask (V after MFMA, for VGPR headroom)
        if (c + 1 < nt) {
            const float* Kn = Kp + (size_t)(c + 1) * 32 * Dn;
            #pragma unroll
            for (int i = 0; i < 4; ++i) {
                ka.v[i] = *(const float4*)(Kn + (size_t)r0 * Dn + cb + 4 * i);
                kb.v[i] = *(const float4*)(Kn + (size_t)r1 * Dn + cb + 4 * i);
            }
            m0 = mp[(c + 1) * 32 + r0]; m1 = mp[(c + 1) * 32 + r1];
        }

        // 16 MFMA: full 64x64 outer tile over this 32-n chunk
        bf16x8 af[4], bfr[4];
        #pragma unroll
        for (int tj = 0; tj < 4; ++tj)
            af[tj] = *(const bf16x8*)&sVT[(16 * tj + p) * 32 + ((8 * q) ^ (tj << 3))];
        #pragma unroll
        for (int P = 0; P < 4; ++P)
            bfr[P] = *(const bf16x8*)&sKT[(16 * P + p) * 32 + ((8 * q) ^ (P << 3))];
        #pragma unroll
        for (int tj = 0; tj < 4; ++tj)
            #pragma unroll
            for (int P = 0; P < 4; ++P)
                acc[tj][P] = __builtin_amdgcn_mfma_f32_16x16x32_bf16(af[tj], bfr[P], acc[tj][P], 0, 0, 0);

        if (c + 1 < nt) {
            const float* Vn = Vp + (size_t)(c + 1) * 32 * Dn;
            #pragma unroll
            for (int i = 0; i < 4; ++i) {
                va.v[i] = *(const float4*)(Vn + (size_t)r0 * Dn + cb + 4 * i);
                vb.v[i] = *(const float4*)(Vn + (size_t)r1 * Dn + cb + 4 * i);
            }
        }
    }

    // cross-wave accumulate (only barriers in the kernel), fixed order
    __syncthreads();
    float* sAcc = (float*)S;   // 16 KB, reuses staging space
    #pragma unroll
    for (int ww = 0; ww < 4; ++ww) {
        if (w == ww) {
            #pragma unroll
            for (int tj = 0; tj < 4; ++tj)
                #pragma unroll
                for (int P = 0; P < 4; ++P)
                    #pragma unroll
                    for (int r = 0; r < 4; ++r) {
                        // C layout: row e = 16*tj + 4*q + r, col d = 16*P + p
                        float* ptr = &sAcc[(16 * tj + 4 * q + r) * 64 + 16 * P + p];
                        *ptr = (ww == 0) ? acc[tj][P][r] : (*ptr + acc[tj][P][r]);
                    }
        }
        __syncthreads();
    }

    float* pp = partial + (size_t)(head * ch + chunk) * (Dn * Dn);
    #pragma unroll
    for (int u = 0; u < 4; ++u) {
        const int f = t + u * 256;
        *(float4*)(pp + 4 * f) = *(const float4*)(sAcc + 4 * f);
    }
}

// ---------------- Phase 1b: reduce partials, emit bf16 KtV^T ----------------
__global__ __launch_bounds__(256) void ktv_reduce_kernel(
    const float* __restrict__ partial, ushort* __restrict__ ktvT, int ch)
{
    const int head = blockIdx.y;
    const int e = blockIdx.x * 256 + threadIdx.x;   // 0..4095
    const float* pp = partial + (size_t)head * ch * (Dn * Dn) + e;
    float s = 0.f;
    for (int c = 0; c < ch; ++c) s += pp[(size_t)c * (Dn * Dn)];
    unsigned u = __float_as_uint(s);
    u = (u + 0x7fffu + ((u >> 16) & 1u)) >> 16;     // RNE
    ktvT[(size_t)head * (Dn * Dn) + e] = (ushort)u;
}

// ---------------- Phase 2: Out = (inv(n)*q) @ KtV  (no LDS) -----------------
__global__ __launch_bounds__(256) void qktv_kernel(
    const float* __restrict__ Q, const ushort* __restrict__ ktvT,
    float* __restrict__ out, float scale)
{
    const int chunk = blockIdx.x, head = blockIdx.y;
    const int n0 = chunk * (Nn / 16);               // 512 rows per block
    const float* Qp = Q + ((size_t)head * Nn + n0) * Dn;
    float* Op = out + ((size_t)head * Nn + n0) * Dn;
    const ushort* kp = ktvT + (size_t)head * (Dn * Dn);

    const int t = threadIdx.x, w = t >> 6, l = t & 63;
    const int lr = l & 15;          // A row-local / B col-local
    const int lg = l >> 4;          // k-group

    bf16x8 bf[4][2];
    #pragma unroll
    for (int E = 0; E < 4; ++E)
        #pragma unroll
        for (int h = 0; h < 2; ++h)
            bf[E][h] = *(const bf16x8*)&kp[(16 * E + lr) * 64 + 32 * h + 8 * lg];

    for (int i = 0; i < 8; ++i) {
        const int strip = i * 4 + w;                // 0..31, 16 rows each
        const float* qrow = Qp + (size_t)(strip * 16 + lr) * Dn;
        const float4 f0 = *(const float4*)(qrow + 8 * lg);
        const float4 f1 = *(const float4*)(qrow + 8 * lg + 4);
        const float4 f2 = *(const float4*)(qrow + 32 + 8 * lg);
        const float4 f3 = *(const float4*)(qrow + 32 + 8 * lg + 4);

        float ss = f0.x*f0.x + f0.y*f0.y + f0.z*f0.z + f0.w*f0.w
                 + f1.x*f1.x + f1.y*f1.y + f1.z*f1.z + f1.w*f1.w
                 + f2.x*f2.x + f2.y*f2.y + f2.z*f2.z + f2.w*f2.w
                 + f3.x*f3.x + f3.y*f3.y + f3.z*f3.z + f3.w*f3.w;
        ss += __shfl_xor(ss, 16, 64);
        ss += __shfl_xor(ss, 32, 64);
        const float inv = scale / fmaxf(sqrtf(ss), 1e-12f);

        union { unsigned u[4]; bf16x8 v; } a0, a1;
        a0.u[0] = cvt_pk_bf16(f0.x*inv, f0.y*inv);
        a0.u[1] = cvt_pk_bf16(f0.z*inv, f0.w*inv);
        a0.u[2] = cvt_pk_bf16(f1.x*inv, f1.y*inv);
        a0.u[3] = cvt_pk_bf16(f1.z*inv, f1.w*inv);
        a1.u[0] = cvt_pk_bf16(f2.x*inv, f2.y*inv);
        a1.u[1] = cvt_pk_bf16(f2.z*inv, f2.w*inv);
        a1.u[2] = cvt_pk_bf16(f3.x*inv, f3.y*inv);
        a1.u[3] = cvt_pk_bf16(f3.z*inv, f3.w*inv);

        #pragma unroll
        for (int E = 0; E < 4; ++E) {
            f32x4 cacc = {0.f, 0.f, 0.f, 0.f};
            cacc = __builtin_amdgcn_mfma_f32_16x16x32_bf16(a0.v, bf[E][0], cacc, 0, 0, 0);
            cacc = __builtin_amdgcn_mfma_f32_16x16x32_bf16(a1.v, bf[E][1], cacc, 0, 0, 0);
            #pragma unroll
            for (int r = 0; r < 4; ++r)
                Op[(size_t)(strip * 16 + 4 * lg + r) * Dn + 16 * E + lr] = cacc[r];
        }
    }
}

extern "C" void kernel_launch(void* const* d_in, const int* in_sizes, int n_in,
                              void* d_out, int out_size, void* d_ws, size_t ws_size,
                              hipStream_t stream)
{
    const float* Q    = (const float*)d_in[0];
    const float* K    = (const float*)d_in[1];
    const float* V    = (const float*)d_in[2];
    const float* mask = (const float*)d_in[3];
    float* out = (float*)d_out;

    const float scale = 1.0f / sqrtf(sqrtf((float)Nn));

    // ws layout: [ ktvT bf16: BH*4096 ushort ][ partial: BH*ch*4096 f32 ]
    const size_t KTV_BYTES = (size_t)BH * Dn * Dn * sizeof(ushort);
    int ch = 32;
    while (ch > 1 && KTV_BYTES + (size_t)BH * ch * Dn * Dn * 4 > ws_size)
        ch >>= 1;

    ushort* ktvT   = (ushort*)d_ws;
    float* partial = (float*)((char*)d_ws + KTV_BYTES);

    ktv_kernel<<<dim3(ch, BH), 256, 0, stream>>>(K, V, mask, partial, scale, ch);
    ktv_reduce_kernel<<<dim3((Dn * Dn) / 256, BH), 256, 0, stream>>>(partial, ktvT, ch);
    qktv_kernel<<<dim3(16, BH), 256, 0, stream>>>(Q, ktvT, out, scale);
}

// Round 5
// 100.931 us; speedup vs baseline: 1.1549x; 1.1549x over previous
//
#include <hip/hip_runtime.h>
#include <cmath>

#define Bn 4
#define Hn 12
#define BH 48
#define Nn 8192
#define Dn 64

typedef float f32x4 __attribute__((ext_vector_type(4)));
typedef short bf16x8 __attribute__((ext_vector_type(8)));

__device__ __forceinline__ unsigned cvt_pk_bf16(float lo, float hi) {
    unsigned r;
    asm("v_cvt_pk_bf16_f32 %0, %1, %2" : "=v"(r) : "v"(lo), "v"(hi));
    return r;
}

// ---------------- Phase 1: partial KtV^T[e][d] = sum_n (rf*k)[n,d]*v[n,e] ---
// LDS-free main loop: MFMA fragments loaded DIRECTLY from global in fragment
// order. Per (E,j) wave-load: 64 lanes read 4 fully-used 64-B lines.
// rf = scale*m^2/max(||k||,eps), applied in-lane before bf16 packing.
__global__ __launch_bounds__(256, 2) void ktv_kernel(
    const float* __restrict__ K, const float* __restrict__ V,
    const float* __restrict__ mask, float* __restrict__ partial,
    float scale, int ch)
{
    const int chunk = blockIdx.x, head = blockIdx.y;
    const int bb = head / Hn;
    const int rowsPer = Nn / ch;            // 512 at ch=16
    const int waveRows = rowsPer >> 2;      // 128

    const int t = threadIdx.x;
    const int w = t >> 6, l = t & 63;
    const int p = l & 15, q = l >> 4;

    const size_t nbase = (size_t)chunk * rowsPer + (size_t)w * waveRows;
    const float* Kp = K + ((size_t)head * Nn + nbase) * Dn;
    const float* Vp = V + ((size_t)head * Nn + nbase) * Dn;
    const float* mp = mask + (size_t)bb * Nn + nbase;

    f32x4 acc[4][4];   // [E (e-panel)][P (d-panel)]
    #pragma unroll
    for (int a = 0; a < 4; ++a)
        #pragma unroll
        for (int b2 = 0; b2 < 4; ++b2) acc[a][b2] = (f32x4){0.f, 0.f, 0.f, 0.f};

    const int nt = waveRows >> 5;           // 32-row chunks
    for (int c = 0; c < nt; ++c) {
        const float* Kc = Kp + (size_t)c * 32 * Dn;
        const float* Vc = Vp + (size_t)c * 32 * Dn;

        // direct fragment-order loads: element (row = 8q+j, col = 16E+p)
        float kx[4][8], vx[4][8], mj[8];
        #pragma unroll
        for (int j = 0; j < 8; ++j) {
            const int row = 8 * q + j;
            mj[j] = mp[c * 32 + row];
            #pragma unroll
            for (int E = 0; E < 4; ++E) {
                kx[E][j] = Kc[(size_t)row * Dn + 16 * E + p];
                vx[E][j] = Vc[(size_t)row * Dn + 16 * E + p];
            }
        }

        // row norms: 16-lane (p) reduce per j; all lanes of a q-group share row
        float rf[8];
        #pragma unroll
        for (int j = 0; j < 8; ++j) {
            float ss = kx[0][j]*kx[0][j] + kx[1][j]*kx[1][j]
                     + kx[2][j]*kx[2][j] + kx[3][j]*kx[3][j];
            ss += __shfl_xor(ss, 1, 64);
            ss += __shfl_xor(ss, 2, 64);
            ss += __shfl_xor(ss, 4, 64);
            ss += __shfl_xor(ss, 8, 64);
            rf[j] = scale * mj[j] * mj[j] / fmaxf(sqrtf(ss), 1e-12f);
        }

        // in-lane bf16 fragment build (consecutive j pairs -> consecutive u32)
        union Frag { unsigned u[4]; bf16x8 v; } aF[4], bF[4];
        #pragma unroll
        for (int E = 0; E < 4; ++E)
            #pragma unroll
            for (int h = 0; h < 4; ++h) {
                aF[E].u[h] = cvt_pk_bf16(vx[E][2*h],            vx[E][2*h+1]);
                bF[E].u[h] = cvt_pk_bf16(kx[E][2*h] * rf[2*h],  kx[E][2*h+1] * rf[2*h+1]);
            }

        #pragma unroll
        for (int E = 0; E < 4; ++E)
            #pragma unroll
            for (int P = 0; P < 4; ++P)
                acc[E][P] = __builtin_amdgcn_mfma_f32_16x16x32_bf16(
                    aF[E].v, bF[P].v, acc[E][P], 0, 0, 0);
    }

    // cross-wave accumulate via LDS (only barriers in kernel), fixed order
    __shared__ __align__(16) float sAcc[Dn * Dn];   // 16 KB
    __syncthreads();
    #pragma unroll
    for (int ww = 0; ww < 4; ++ww) {
        if (w == ww) {
            #pragma unroll
            for (int E = 0; E < 4; ++E)
                #pragma unroll
                for (int P = 0; P < 4; ++P)
                    #pragma unroll
                    for (int r = 0; r < 4; ++r) {
                        // C layout: row e = 16E + 4q + r, col d = 16P + p
                        float* ptr = &sAcc[(16 * E + 4 * q + r) * 64 + 16 * P + p];
                        *ptr = (ww == 0) ? acc[E][P][r] : (*ptr + acc[E][P][r]);
                    }
        }
        __syncthreads();
    }

    float* pp = partial + (size_t)(head * ch + chunk) * (Dn * Dn);
    #pragma unroll
    for (int u = 0; u < 4; ++u) {
        const int f = t + u * 256;
        *(float4*)(pp + 4 * f) = *(const float4*)(sAcc + 4 * f);
    }
}

// ---------------- Phase 1b: reduce partials, emit bf16 KtV^T ----------------
__global__ __launch_bounds__(256) void ktv_reduce_kernel(
    const float* __restrict__ partial, ushort* __restrict__ ktvT, int ch)
{
    const int head = blockIdx.y;
    const int e = blockIdx.x * 256 + threadIdx.x;   // 0..4095
    const float* pp = partial + (size_t)head * ch * (Dn * Dn) + e;
    float s = 0.f;
    for (int c = 0; c < ch; ++c) s += pp[(size_t)c * (Dn * Dn)];
    unsigned u = __float_as_uint(s);
    u = (u + 0x7fffu + ((u >> 16) & 1u)) >> 16;     // RNE
    ktvT[(size_t)head * (Dn * Dn) + e] = (ushort)u;
}

// ---------------- Phase 2: Out = (inv(n)*q) @ KtV  (no LDS) -----------------
__global__ __launch_bounds__(256) void qktv_kernel(
    const float* __restrict__ Q, const ushort* __restrict__ ktvT,
    float* __restrict__ out, float scale)
{
    const int chunk = blockIdx.x, head = blockIdx.y;
    const int n0 = chunk * (Nn / 16);               // 512 rows per block
    const float* Qp = Q + ((size_t)head * Nn + n0) * Dn;
    float* Op = out + ((size_t)head * Nn + n0) * Dn;
    const ushort* kp = ktvT + (size_t)head * (Dn * Dn);

    const int t = threadIdx.x, w = t >> 6, l = t & 63;
    const int lr = l & 15;          // A row-local / B col-local
    const int lg = l >> 4;          // k-group

    bf16x8 bf[4][2];
    #pragma unroll
    for (int E = 0; E < 4; ++E)
        #pragma unroll
        for (int h = 0; h < 2; ++h)
            bf[E][h] = *(const bf16x8*)&kp[(16 * E + lr) * 64 + 32 * h + 8 * lg];

    for (int i = 0; i < 8; ++i) {
        const int strip = i * 4 + w;                // 0..31, 16 rows each
        const float* qrow = Qp + (size_t)(strip * 16 + lr) * Dn;
        const float4 f0 = *(const float4*)(qrow + 8 * lg);
        const float4 f1 = *(const float4*)(qrow + 8 * lg + 4);
        const float4 f2 = *(const float4*)(qrow + 32 + 8 * lg);
        const float4 f3 = *(const float4*)(qrow + 32 + 8 * lg + 4);

        float ss = f0.x*f0.x + f0.y*f0.y + f0.z*f0.z + f0.w*f0.w
                 + f1.x*f1.x + f1.y*f1.y + f1.z*f1.z + f1.w*f1.w
                 + f2.x*f2.x + f2.y*f2.y + f2.z*f2.z + f2.w*f2.w
                 + f3.x*f3.x + f3.y*f3.y + f3.z*f3.z + f3.w*f3.w;
        ss += __shfl_xor(ss, 16, 64);
        ss += __shfl_xor(ss, 32, 64);
        const float inv = scale / fmaxf(sqrtf(ss), 1e-12f);

        union { unsigned u[4]; bf16x8 v; } a0, a1;
        a0.u[0] = cvt_pk_bf16(f0.x*inv, f0.y*inv);
        a0.u[1] = cvt_pk_bf16(f0.z*inv, f0.w*inv);
        a0.u[2] = cvt_pk_bf16(f1.x*inv, f1.y*inv);
        a0.u[3] = cvt_pk_bf16(f1.z*inv, f1.w*inv);
        a1.u[0] = cvt_pk_bf16(f2.x*inv, f2.y*inv);
        a1.u[1] = cvt_pk_bf16(f2.z*inv, f2.w*inv);
        a1.u[2] = cvt_pk_bf16(f3.x*inv, f3.y*inv);
        a1.u[3] = cvt_pk_bf16(f3.z*inv, f3.w*inv);

        #pragma unroll
        for (int E = 0; E < 4; ++E) {
            f32x4 cacc = {0.f, 0.f, 0.f, 0.f};
            cacc = __builtin_amdgcn_mfma_f32_16x16x32_bf16(a0.v, bf[E][0], cacc, 0, 0, 0);
            cacc = __builtin_amdgcn_mfma_f32_16x16x32_bf16(a1.v, bf[E][1], cacc, 0, 0, 0);
            #pragma unroll
            for (int r = 0; r < 4; ++r)
                Op[(size_t)(strip * 16 + 4 * lg + r) * Dn + 16 * E + lr] = cacc[r];
        }
    }
}

extern "C" void kernel_launch(void* const* d_in, const int* in_sizes, int n_in,
                              void* d_out, int out_size, void* d_ws, size_t ws_size,
                              hipStream_t stream)
{
    const float* Q    = (const float*)d_in[0];
    const float* K    = (const float*)d_in[1];
    const float* V    = (const float*)d_in[2];
    const float* mask = (const float*)d_in[3];
    float* out = (float*)d_out;

    const float scale = 1.0f / sqrtf(sqrtf((float)Nn));

    // ws layout: [ ktvT bf16: BH*4096 ushort ][ partial: BH*ch*4096 f32 ]
    const size_t KTV_BYTES = (size_t)BH * Dn * Dn * sizeof(ushort);
    int ch = 16;
    while (ch > 1 && KTV_BYTES + (size_t)BH * ch * Dn * Dn * 4 > ws_size)
        ch >>= 1;

    ushort* ktvT   = (ushort*)d_ws;
    float* partial = (float*)((char*)d_ws + KTV_BYTES);

    ktv_kernel<<<dim3(ch, BH), 256, 0, stream>>>(K, V, mask, partial, scale, ch);
    ktv_reduce_kernel<<<dim3((Dn * Dn) / 256, BH), 256, 0, stream>>>(partial, ktvT, ch);
    qktv_kernel<<<dim3(16, BH), 256, 0, stream>>>(Q, ktvT, out, scale);
}